// Round 6
// baseline (388.970 us; speedup 1.0000x reference)
//
#include <hip/hip_runtime.h>
#include <cstdint>
#include <cmath>

// QuantumLatentLayer: out[b,q] = cos(a)*cos(th_q) - sin(a)*(cos(phi_q)*sin(th_q))
//                     a = sum_l latent[b,l]*W[q,l] + b_q
// M=32768, K=2048, N=24. HBM floor ~38 us @ 7 TB/s; VALU floor ~20.5 us.
//
// Lessons: R2 (counted vmcnt, 74us) >> R4/R5 (drain vmcnt(0), ~115us): counted
// waits keep a chunk in flight; drain convoys. R2's own limit: per-lane W
// ds_reads flood the DS pipe. R4: W s_loads = serial lgkm batches.
// v6: latent DIRECT to registers (lane owns 4 rows, compiler-managed vmcnt on
// reg deps), W via wave-uniform LDS broadcast (6 ds_read_b128 per k serve
// 96 FMAs), counted vmcnt(9), 2-deep software pipeline with named A/B bufs.
// k-split 4 across blocks -> fp32 partials in ws + tiny finish kernel.

#define NQ 24
#define LDIM 2048
#define BATCH 32768
#define KC 8                  // k-floats per chunk
#define ROWS_PER_LANE 4
#define GROUP_ROWS 256        // 4 rows/lane * 64 lanes
#define KSLICES 4
#define KSPAN (LDIM / KSLICES)      // 512 per block; per wave 128
#define WSPAN (KSPAN / 4)           // 128 k per wave
#define NCH (WSPAN / KC)            // 16 chunks
#define PART_STRIDE (GROUP_ROWS * NQ)   // 6144 floats per block partial

typedef const __attribute__((address_space(1))) void* gas_t;
typedef __attribute__((address_space(3))) void* las_t;

__device__ __forceinline__ void gload_lds16(const float* g, float* l) {
    __builtin_amdgcn_global_load_lds((gas_t)g, (las_t)l, 16, 0, 0);
}

#define CVMCNT(n) asm volatile("s_waitcnt vmcnt(" #n ")" ::: "memory")

struct LatBuf { float4 v[ROWS_PER_LANE][2]; };   // 4 rows x 8 floats

__device__ __forceinline__ void issue_lat(LatBuf& b, const float* const (&lp)[4], int c) {
    #pragma unroll
    for (int r = 0; r < 4; r++) {
        b.v[r][0] = *(const float4*)(lp[r] + c * KC);
        b.v[r][1] = *(const float4*)(lp[r] + c * KC + 4);
    }
}

// W chunk [8 k][24 q] = 768 B contiguous; ONE global_load_lds16, lanes 0..47.
__device__ __forceinline__ void stage_w(const float* wsrc, float* wdst, int lane) {
    if (lane < 48) gload_lds16(wsrc + lane * 4, wdst);
}

// Per chunk: 48 wave-uniform ds_read_b128 (W broadcast) + 768 FMA.
__device__ __forceinline__ void compute_chunk(const LatBuf& b, const float4* wb,
                                              float (&acc)[ROWS_PER_LANE][NQ]) {
    #pragma unroll
    for (int k = 0; k < KC; k++) {
        float4 w0 = wb[k * 6 + 0], w1 = wb[k * 6 + 1], w2 = wb[k * 6 + 2];
        float4 w3 = wb[k * 6 + 3], w4 = wb[k * 6 + 4], w5 = wb[k * 6 + 5];
        const float wv[NQ] = {w0.x, w0.y, w0.z, w0.w, w1.x, w1.y, w1.z, w1.w,
                              w2.x, w2.y, w2.z, w2.w, w3.x, w3.y, w3.z, w3.w,
                              w4.x, w4.y, w4.z, w4.w, w5.x, w5.y, w5.z, w5.w};
        #pragma unroll
        for (int r = 0; r < 4; r++) {
            const float a = ((const float*)&b.v[r][k >> 2])[k & 3];
            #pragma unroll
            for (int q = 0; q < NQ; q++)
                acc[r][q] = fmaf(a, wv[q], acc[r][q]);
        }
    }
}

__global__ __launch_bounds__(256, 2) void qll_main(
    const float* __restrict__ latent,
    const float* __restrict__ wt,     // [LDIM][NQ]
    float* __restrict__ part)         // [gridDim.x][6144]
{
    __shared__ __align__(16) float4 wlds[4][2][48];   // 6 KB (W dbuf per wave)
    __shared__ __align__(16) float racc[PART_STRIDE]; // 24 KB

    const int tid  = threadIdx.x;
    const int wave = tid >> 6;
    const int lane = tid & 63;
    const int g    = blockIdx.x >> 2;        // rowgroup 0..127
    const int kq   = blockIdx.x & 3;         // k-slice 0..3
    const int row0 = g * GROUP_ROWS;
    const int koff = kq * KSPAN + wave * WSPAN;

    const float* lp[4];
    #pragma unroll
    for (int r = 0; r < 4; r++)
        lp[r] = latent + (size_t)(row0 + r * 64 + lane) * LDIM + koff;
    const float* wsrc = wt + (size_t)koff * NQ;

    float* wb0 = (float*)&wlds[wave][0][0];
    float* wb1 = (float*)&wlds[wave][1][0];
    const float4* wb0f = &wlds[wave][0][0];
    const float4* wb1f = &wlds[wave][1][0];

    float acc[ROWS_PER_LANE][NQ];
    #pragma unroll
    for (int r = 0; r < 4; r++)
        #pragma unroll
        for (int q = 0; q < NQ; q++) acc[r][q] = 0.0f;

    LatBuf A, B;
    issue_lat(A, lp, 0);
    stage_w(wsrc, wb0, lane);                 // 9 VMEM outstanding

    #pragma unroll 1
    for (int i = 0; i < NCH / 2 - 1; i++) {
        issue_lat(B, lp, 2 * i + 1);
        stage_w(wsrc + (size_t)(2 * i + 1) * KC * NQ, wb1, lane);
        CVMCNT(9);                            // prev 9 done; these 9 in flight
        compute_chunk(A, wb0f, acc);
        issue_lat(A, lp, 2 * i + 2);
        stage_w(wsrc + (size_t)(2 * i + 2) * KC * NQ, wb0, lane);
        CVMCNT(9);
        compute_chunk(B, wb1f, acc);
    }
    issue_lat(B, lp, NCH - 1);
    stage_w(wsrc + (size_t)(NCH - 1) * KC * NQ, wb1, lane);
    CVMCNT(9);
    compute_chunk(A, wb0f, acc);
    CVMCNT(0);
    compute_chunk(B, wb1f, acc);

    // In-block reduction over the 4 waves' k-subslices (once; 4 sync rounds).
    #pragma unroll 1
    for (int w = 0; w < 4; w++) {
        if (wave == w) {
            #pragma unroll
            for (int r = 0; r < 4; r++) {
                float* dst = &racc[(r * 64 + lane) * NQ];
                #pragma unroll
                for (int v = 0; v < 6; v++) {
                    float4 t = make_float4(acc[r][4*v], acc[r][4*v+1],
                                           acc[r][4*v+2], acc[r][4*v+3]);
                    if (w) {
                        float4 o = ((float4*)dst)[v];
                        t.x += o.x; t.y += o.y; t.z += o.z; t.w += o.w;
                    }
                    ((float4*)dst)[v] = t;
                }
            }
        }
        __syncthreads();
    }

    // Write block partial (coalesced b32).
    float* wp = part + (size_t)blockIdx.x * PART_STRIDE;
    #pragma unroll 1
    for (int j = 0; j < NQ; j++) {
        const int f = tid + 256 * j;
        wp[f] = racc[f];
    }
}

// Finish: sum 4 k-slice partials + bias, trig epilogue. 786432 threads.
__global__ __launch_bounds__(256) void qll_fin(
    const float* __restrict__ part,
    const float* __restrict__ bvec,
    const float* __restrict__ ctv,
    const float* __restrict__ csv,
    float* __restrict__ out)
{
    const int i   = blockIdx.x * 256 + threadIdx.x;   // 0..786431
    const int row = i / NQ;
    const int q   = i - row * NQ;
    const int g   = row >> 8;
    const int f   = i - g * PART_STRIDE;
    const size_t base = (size_t)(g * 4) * PART_STRIDE + f;
    float a = part[base] + part[base + PART_STRIDE] + part[base + 2 * PART_STRIDE]
            + part[base + 3 * PART_STRIDE] + bvec[q];
    float s, co;
    __sincosf(a, &s, &co);
    out[i] = co * ctv[q] - s * csv[q];
}

// Prep: Wt[k][q] = W[q][k]; ctcs[0..23]=cos(theta), ctcs[24..47]=cos(phi)*sin(theta)
__global__ __launch_bounds__(256) void qll_prep(
    const float* __restrict__ W, const float* __restrict__ params,
    float* __restrict__ wt, float* __restrict__ ctcs)
{
    int idx = blockIdx.x * 256 + threadIdx.x;
    if (idx < LDIM * NQ) {
        int q = idx % NQ;
        int k = idx / NQ;
        wt[idx] = W[q * LDIM + k];
    }
    if (idx < NQ) {
        float phi = params[3 * idx + 0];
        float th  = params[3 * idx + 1];
        ctcs[idx]      = cosf(th);
        ctcs[NQ + idx] = cosf(phi) * sinf(th);
    }
}

extern "C" void kernel_launch(void* const* d_in, const int* in_sizes, int n_in,
                              void* d_out, int out_size, void* d_ws, size_t ws_size,
                              hipStream_t stream) {
    (void)in_sizes; (void)n_in; (void)out_size; (void)ws_size;
    const float* latent = (const float*)d_in[0];
    const float* W      = (const float*)d_in[1];
    const float* bvec   = (const float*)d_in[2];
    const float* params = (const float*)d_in[3];
    float* out  = (float*)d_out;
    float* wt   = (float*)d_ws;                   // 49152 floats
    float* ctcs = wt + LDIM * NQ;                 // 48 floats
    float* part = (float*)d_ws + 65536;           // 512*6144 floats = 12.6 MB

    hipLaunchKernelGGL(qll_prep, dim3((LDIM * NQ + 255) / 256), dim3(256), 0, stream,
                       W, params, wt, ctcs);
    hipLaunchKernelGGL(qll_main, dim3((BATCH / GROUP_ROWS) * KSLICES), dim3(256), 0, stream,
                       latent, wt, part);
    hipLaunchKernelGGL(qll_fin, dim3(BATCH * NQ / 256), dim3(256), 0, stream,
                       part, bvec, ctcs, ctcs + NQ, out);
}

// Round 7
// 52.880 us; speedup vs baseline: 7.3557x; 7.3557x over previous
//
#include <hip/hip_runtime.h>
#include <cstdint>

// QuantumLatentLayer via MFMA: out[b,q] = cos(a)cos(th_q) - sin(a)cos(phi_q)sin(th_q),
// a = latent(32768x2048) . W^T(24x2048) + b.
// All-rounds lesson: any vector-FMA W-delivery (LDS per-lane R2, LDS broadcast R5,
// s_load R4) costs ~36us on its pipe ~= HBM floor; R6 direct-to-reg over-fetched 3.3x.
// MFMA's hardware operand broadcast removes W delivery entirely; A-fragment shape
// (16 rows x 32 k per wave) makes the wave's 2 global_load_dwordx4 cover 16 FULL
// cachelines (zero waste, zero LDS). Latent hi/lo bf16 split keeps |err| ~ W-rounding
// only (~0.007 << 0.02). W prepacked per-fragment; bias+trig fused in epilogue.

#define NQ 24
#define LDIM 2048
#define BATCH 32768
#define NKT 64            // 2048 / 32 k-tiles

typedef __attribute__((ext_vector_type(8))) short bf16x8;
typedef __attribute__((ext_vector_type(4))) float f32x4;

union U4 { uint4 u; bf16x8 s; };

__device__ __forceinline__ uint cvt_pk_bf16(float lo, float hi) {
    uint r;
    asm("v_cvt_pk_bf16_f32 %0, %1, %2" : "=v"(r) : "v"(lo), "v"(hi));
    return r;
}

struct Stage { float4 a0, a1; uint4 b0, b1; };

// Issue one k-tile's loads (4 VMEM insts). A: lane -> row=lane&15, k=kgrp*8..+7;
// the wave's a0+a1 pair covers rows r0..r15 x k 0..31 = 16 full 128B lines.
__device__ __forceinline__ void issue(Stage& s, const float* ap, const uint4* bp, int t) {
    s.a0 = *(const float4*)(ap + t * 32);
    s.a1 = *(const float4*)(ap + t * 32 + 4);
    s.b0 = bp[t * 128];        // qtile 0 fragment
    s.b1 = bp[t * 128 + 64];   // qtile 1 fragment
}

__device__ __forceinline__ void computeS(const Stage& s, f32x4& c0, f32x4& c1) {
    // hi/lo bf16 split of the 8 fp32 A elements (RNE via v_cvt_pk_bf16_f32)
    uint h0 = cvt_pk_bf16(s.a0.x, s.a0.y);
    uint h1 = cvt_pk_bf16(s.a0.z, s.a0.w);
    uint h2 = cvt_pk_bf16(s.a1.x, s.a1.y);
    uint h3 = cvt_pk_bf16(s.a1.z, s.a1.w);
    float r0 = __uint_as_float(h0 << 16), r1 = __uint_as_float(h0 & 0xFFFF0000u);
    float r2 = __uint_as_float(h1 << 16), r3 = __uint_as_float(h1 & 0xFFFF0000u);
    float r4 = __uint_as_float(h2 << 16), r5 = __uint_as_float(h2 & 0xFFFF0000u);
    float r6 = __uint_as_float(h3 << 16), r7 = __uint_as_float(h3 & 0xFFFF0000u);
    uint l0 = cvt_pk_bf16(s.a0.x - r0, s.a0.y - r1);
    uint l1 = cvt_pk_bf16(s.a0.z - r2, s.a0.w - r3);
    uint l2 = cvt_pk_bf16(s.a1.x - r4, s.a1.y - r5);
    uint l3 = cvt_pk_bf16(s.a1.z - r6, s.a1.w - r7);
    U4 ah, al, b0, b1;
    ah.u = make_uint4(h0, h1, h2, h3);
    al.u = make_uint4(l0, l1, l2, l3);
    b0.u = s.b0;
    b1.u = s.b1;
    c0 = __builtin_amdgcn_mfma_f32_16x16x32_bf16(ah.s, b0.s, c0, 0, 0, 0);
    c1 = __builtin_amdgcn_mfma_f32_16x16x32_bf16(ah.s, b1.s, c1, 0, 0, 0);
    c0 = __builtin_amdgcn_mfma_f32_16x16x32_bf16(al.s, b0.s, c0, 0, 0, 0);
    c1 = __builtin_amdgcn_mfma_f32_16x16x32_bf16(al.s, b1.s, c1, 0, 0, 0);
}

__global__ __launch_bounds__(256, 2) void qll_main(
    const float* __restrict__ latent,
    const uint4* __restrict__ wb,     // prepacked W fragments, bf16, 128 KB
    const float* __restrict__ bvec,
    const float* __restrict__ ctv,    // cos(theta)
    const float* __restrict__ csv,    // cos(phi)*sin(theta)
    float* __restrict__ out)
{
    const int tid  = threadIdx.x;
    const int wave = tid >> 6;
    const int lane = tid & 63;
    const int mrow = lane & 15;
    const int kgrp = lane >> 4;
    const int row0 = (blockIdx.x * 4 + wave) * 16;

    const float* ap = latent + (size_t)(row0 + mrow) * LDIM + kgrp * 8;
    const uint4* bp = wb + lane;

    f32x4 c0 = {0.f, 0.f, 0.f, 0.f};
    f32x4 c1 = {0.f, 0.f, 0.f, 0.f};

    // 3-deep pipeline, named stages (static indexing). Ordinary register loads:
    // the compiler inserts exact counted vmcnt before each use (no LDS anywhere).
    Stage S0, S1, S2;
    issue(S0, ap, bp, 0);
    issue(S1, ap, bp, 1);
    issue(S2, ap, bp, 2);

    #pragma unroll 1
    for (int t = 0; t <= NKT - 7; t += 3) {   // t = 0..57: compute 0..59, issue 3..62
        computeS(S0, c0, c1); issue(S0, ap, bp, t + 3);
        computeS(S1, c0, c1); issue(S1, ap, bp, t + 4);
        computeS(S2, c0, c1); issue(S2, ap, bp, t + 5);
    }
    computeS(S0, c0, c1); issue(S0, ap, bp, 63);  // 60
    computeS(S1, c0, c1);                          // 61
    computeS(S2, c0, c1);                          // 62
    computeS(S0, c0, c1);                          // 63

    // Epilogue: C/D layout (m89): col q = lane&15 (+16*qt), row = kgrp*4 + r.
    #pragma unroll
    for (int qt = 0; qt < 2; qt++) {
        const int q = qt * 16 + mrow;
        const bool valid = (q < NQ);
        const float bv = valid ? bvec[q] : 0.f;
        const float ct = valid ? ctv[q]  : 0.f;
        const float cs = valid ? csv[q]  : 0.f;
        const f32x4 c = qt ? c1 : c0;
        #pragma unroll
        for (int r = 0; r < 4; r++) {
            const int row = row0 + kgrp * 4 + r;
            const float a = c[r] + bv;
            float s, co;
            __sincosf(a, &s, &co);
            if (valid) out[(size_t)row * NQ + q] = co * ct - s * cs;
        }
    }
}

// Prep: pack W into per-fragment bf16 layout. Fragment (kt, qt): 64 lanes x 16 B;
// lane l supplies q = qt*16 + (l&15), k = kt*32 + (l>>4)*8 + e (e=0..7), zero-pad q>=24.
// Flat ushort index = ((kt*2 + qt)*64 + l)*8 + e. Also ctcs[0..23]=cos(th),
// ctcs[24..47]=cos(phi)*sin(th).
__global__ __launch_bounds__(256) void qll_prep(
    const float* __restrict__ W, const float* __restrict__ params,
    ushort* __restrict__ wb, float* __restrict__ ctcs)
{
    const int idx = blockIdx.x * 256 + threadIdx.x;   // 0..65535
    const int kt  = idx >> 10;
    const int rem = idx & 1023;
    const int qt  = rem >> 9;
    const int l   = (rem >> 3) & 63;
    const int e   = rem & 7;
    const int q   = qt * 16 + (l & 15);
    const int k   = kt * 32 + (l >> 4) * 8 + e;
    float v = (q < NQ) ? W[q * LDIM + k] : 0.f;
    uint u = __float_as_uint(v);
    wb[idx] = (ushort)((u + 0x7FFF + ((u >> 16) & 1)) >> 16);   // RNE bf16
    if (idx < NQ) {
        float phi = params[3 * idx + 0];
        float th  = params[3 * idx + 1];
        ctcs[idx]      = cosf(th);
        ctcs[NQ + idx] = cosf(phi) * sinf(th);
    }
}

extern "C" void kernel_launch(void* const* d_in, const int* in_sizes, int n_in,
                              void* d_out, int out_size, void* d_ws, size_t ws_size,
                              hipStream_t stream) {
    (void)in_sizes; (void)n_in; (void)out_size; (void)ws_size;
    const float* latent = (const float*)d_in[0];
    const float* W      = (const float*)d_in[1];
    const float* bvec   = (const float*)d_in[2];
    const float* params = (const float*)d_in[3];
    float* out  = (float*)d_out;
    ushort* wb  = (ushort*)d_ws;                     // 65536 bf16 = 128 KB
    float* ctcs = (float*)d_ws + 32768;              // 48 floats

    hipLaunchKernelGGL(qll_prep, dim3(256), dim3(256), 0, stream,
                       W, params, wb, ctcs);
    hipLaunchKernelGGL(qll_main, dim3(BATCH / 64), dim3(256), 0, stream,
                       latent, (const uint4*)wb, bvec, ctcs, ctcs + NQ, out);
}